// Round 8
// baseline (604.043 us; speedup 1.0000x reference)
//
#include <hip/hip_runtime.h>
#include <hip/hip_bf16.h>
#include <stdint.h>

#define NN 100000
#define NE 1600000
#define DD 128
#define HH 256
#define LL 40

typedef __attribute__((ext_vector_type(8))) short short8;
typedef __attribute__((ext_vector_type(4))) float float4v;
typedef __attribute__((ext_vector_type(8))) float float8v;

__device__ __forceinline__ float bfu_lo(uint32_t u){ union{uint32_t i;float f;}v; v.i=u<<16; return v.f; }
__device__ __forceinline__ float bfu_hi(uint32_t u){ union{uint32_t i;float f;}v; v.i=u&0xFFFF0000u; return v.f; }
__device__ __forceinline__ float bf2f(uint16_t u){ union{uint32_t i;float f;}v; v.i=((uint32_t)u)<<16; return v.f; }
__device__ __forceinline__ uint16_t f2bf(float f){
  union{float f;uint32_t i;}v; v.f=f; uint32_t u=v.i;
  u += 0x7FFFu + ((u>>16)&1u); return (uint16_t)(u>>16);
}
__device__ __forceinline__ void split2(float f, short &hi, short &lo){
  uint16_t h = f2bf(f);
  hi = (short)h;
  lo = (short)f2bf(f - bf2f(h));
}
__device__ __forceinline__ float u2f(uint32_t u){ union{uint32_t i;float f;}v; v.i=u; return v.f; }

// ---------------- preprocessing ----------------

__global__ __launch_bounds__(256) void count_edges(const int* __restrict__ row,
                                                   int* __restrict__ counts, int* __restrict__ rank){
  int e = blockIdx.x*256 + threadIdx.x;
  if (e < NE) rank[e] = atomicAdd(&counts[row[e]], 1);
}

__global__ __launch_bounds__(256) void scan_partial(const int* __restrict__ counts,
                                                    int* __restrict__ offs, int* __restrict__ bsums){
  __shared__ int sh[256];
  int t = threadIdx.x, i = blockIdx.x*256 + t;
  int v = (i < NN) ? counts[i] : 0;
  sh[t] = v; __syncthreads();
  for (int d = 1; d < 256; d <<= 1){
    int x = (t >= d) ? sh[t-d] : 0;
    __syncthreads();
    sh[t] += x;
    __syncthreads();
  }
  if (i < NN) offs[i] = sh[t] - v;
  if (t == 255) bsums[blockIdx.x] = sh[255];
}

__global__ __launch_bounds__(512) void scan_block(int* __restrict__ bsums, int nb){
  __shared__ int sh[512];
  int t = threadIdx.x;
  int v = (t < nb) ? bsums[t] : 0;
  sh[t] = v; __syncthreads();
  for (int d = 1; d < 512; d <<= 1){
    int x = (t >= d) ? sh[t-d] : 0;
    __syncthreads();
    sh[t] += x;
    __syncthreads();
  }
  if (t < nb) bsums[t] = sh[t] - v;
}

__global__ __launch_bounds__(256) void scan_add(int* __restrict__ offs, const int* __restrict__ bsums){
  int i = blockIdx.x*256 + threadIdx.x;
  if (i < NN) offs[i] += bsums[blockIdx.x];
  if (i == 0) offs[NN] = NE;
}

__global__ __launch_bounds__(256) void compute_dinv(const int* __restrict__ counts, float* __restrict__ dinv){
  int i = blockIdx.x*256 + threadIdx.x;
  if (i < NN) dinv[i] = rsqrtf((float)(counts[i] + 1));
}

__global__ __launch_bounds__(256) void fill_csr(const int* __restrict__ row, const int* __restrict__ col,
                                                const int* __restrict__ rank,
                                                const int* __restrict__ offs,
                                                const float* __restrict__ dinv,
                                                uint2* __restrict__ csr_cw){
  int e = blockIdx.x*256 + threadIdx.x;
  if (e < NE){
    int r = row[e];
    int c = col[e];
    int p = offs[r] + rank[e];
    uint2 v;
    v.x = (uint32_t)c;
    union{float f;uint32_t i;}w; w.f = dinv[c];
    v.y = w.i;
    csr_cw[p] = v;
  }
}

__global__ __launch_bounds__(256) void cvt_bf16(const float2* __restrict__ x, uint32_t* __restrict__ hb){
  int i = blockIdx.x*256 + threadIdx.x;
  if (i < NN*64){
    float2 v = x[i];
    hb[i] = (uint32_t)f2bf(v.x) | ((uint32_t)f2bf(v.y) << 16);
  }
}

// ---------------- weight pre-swizzle (f32 -> bf16 B-fragments) ----------------
// Wf[frag(kb,nt)*512 + lane*8 + j] = W[k = kb*32 + (lane>>4)*8 + j][n = nt*16 + (lane&15)]

template<int KDIM, int NCOL, int NTBP>
__global__ __launch_bounds__(256) void swz(const float* __restrict__ W, uint16_t* __restrict__ Wf){
  constexpr int KB = KDIM / 32;
  constexpr int TOT = KB * NTBP * 512;
  int idx = blockIdx.x*256 + threadIdx.x;
  if (idx >= TOT) return;
  int frag = idx >> 9, r = idx & 511, ln = r >> 3, j = r & 7;
  int kb = frag / NTBP, nt = frag - kb*NTBP;
  int k = kb*32 + ((ln >> 4) << 3) + j;
  int n = nt*16 + (ln & 15);
  float w = (n < NCOL) ? W[k*NCOL + n] : 0.f;
  Wf[idx] = f2bf(w);
}

// ---------------- aggregation: bf16 gather, f32 accumulate, 8-deep MLP ----------------

__global__ __launch_bounds__(256) void agg_b(const uint32_t* __restrict__ hb,
                                             const int* __restrict__ offs,
                                             const uint2* __restrict__ csr_cw,
                                             const float* __restrict__ dinv,
                                             float2* __restrict__ outp){
  const int w = (blockIdx.x*256 + threadIdx.x) >> 6;
  const int lane = threadIdx.x & 63;
  if (w >= NN) return;
  const int s = offs[w], e = offs[w+1];
  const float dr = dinv[w];
  const uint32_t us = hb[(size_t)w*64 + lane];

  float a0=0.f,a1=0.f,b0=0.f,b1=0.f,c0=0.f,c1=0.f,d0=0.f,d1=0.f;
  float e0=0.f,e1=0.f,f0=0.f,f1=0.f,g0=0.f,g1=0.f,h0=0.f,h1=0.f;
  int i = s;
  for (; i + 8 <= e; i += 8){
    uint2 p0=csr_cw[i],  p1=csr_cw[i+1], p2=csr_cw[i+2], p3=csr_cw[i+3];
    uint2 p4=csr_cw[i+4],p5=csr_cw[i+5], p6=csr_cw[i+6], p7=csr_cw[i+7];
    uint32_t u0=hb[(size_t)p0.x*64+lane], u1=hb[(size_t)p1.x*64+lane];
    uint32_t u2=hb[(size_t)p2.x*64+lane], u3=hb[(size_t)p3.x*64+lane];
    uint32_t u4=hb[(size_t)p4.x*64+lane], u5=hb[(size_t)p5.x*64+lane];
    uint32_t u6=hb[(size_t)p6.x*64+lane], u7=hb[(size_t)p7.x*64+lane];
    a0 += u2f(p0.y)*bfu_lo(u0); a1 += u2f(p0.y)*bfu_hi(u0);
    b0 += u2f(p1.y)*bfu_lo(u1); b1 += u2f(p1.y)*bfu_hi(u1);
    c0 += u2f(p2.y)*bfu_lo(u2); c1 += u2f(p2.y)*bfu_hi(u2);
    d0 += u2f(p3.y)*bfu_lo(u3); d1 += u2f(p3.y)*bfu_hi(u3);
    e0 += u2f(p4.y)*bfu_lo(u4); e1 += u2f(p4.y)*bfu_hi(u4);
    f0 += u2f(p5.y)*bfu_lo(u5); f1 += u2f(p5.y)*bfu_hi(u5);
    g0 += u2f(p6.y)*bfu_lo(u6); g1 += u2f(p6.y)*bfu_hi(u6);
    h0 += u2f(p7.y)*bfu_lo(u7); h1 += u2f(p7.y)*bfu_hi(u7);
  }
  if (i + 4 <= e){
    uint2 p0=csr_cw[i], p1=csr_cw[i+1], p2=csr_cw[i+2], p3=csr_cw[i+3];
    uint32_t u0=hb[(size_t)p0.x*64+lane], u1=hb[(size_t)p1.x*64+lane];
    uint32_t u2=hb[(size_t)p2.x*64+lane], u3=hb[(size_t)p3.x*64+lane];
    a0 += u2f(p0.y)*bfu_lo(u0); a1 += u2f(p0.y)*bfu_hi(u0);
    b0 += u2f(p1.y)*bfu_lo(u1); b1 += u2f(p1.y)*bfu_hi(u1);
    c0 += u2f(p2.y)*bfu_lo(u2); c1 += u2f(p2.y)*bfu_hi(u2);
    d0 += u2f(p3.y)*bfu_lo(u3); d1 += u2f(p3.y)*bfu_hi(u3);
    i += 4;
  }
  for (; i < e; ++i){
    uint2 p = csr_cw[i];
    uint32_t u = hb[(size_t)p.x*64 + lane];
    a0 += u2f(p.y)*bfu_lo(u); a1 += u2f(p.y)*bfu_hi(u);
  }
  float r0 = (((a0+b0)+(c0+d0)) + ((e0+f0)+(g0+h0))) + dr*bfu_lo(us);
  float r1 = (((a1+b1)+(c1+d1)) + ((e1+f1)+(g1+h1))) + dr*bfu_hi(us);
  outp[(size_t)w*64 + lane] = make_float2(r0*dr, r1*dr);
}

// ---------------- square GEMM: H(bf16) <- relu(A(f32) @ W + b) ----------------
// 2 m-tiles per wave (block = 128 rows); W plain bf16; A split hi/lo (2-term).

__global__ __launch_bounds__(256) void gemm_b(const float* __restrict__ A,
                                              const uint16_t* __restrict__ Wf,
                                              const float* __restrict__ bias,
                                              uint16_t* __restrict__ Hout, int M){
  const int lane = threadIdx.x & 63;
  const int wid = threadIdx.x >> 6;
  const int mbase = blockIdx.x*128 + wid*32;
  const int mr = lane & 15;
  const int a0r = (mbase + mr < M) ? (mbase + mr) : (M-1);
  const int a1r = (mbase + 16 + mr < M) ? (mbase + 16 + mr) : (M-1);
  const int ko = (lane >> 4) << 3;

  float4v acc[8][2];
#pragma unroll
  for (int nt = 0; nt < 8; ++nt){ float4v z = {0.f,0.f,0.f,0.f}; acc[nt][0] = z; acc[nt][1] = z; }

#pragma unroll
  for (int kb = 0; kb < 4; ++kb){
    float8v a0 = *(const float8v*)&A[(size_t)a0r*128 + kb*32 + ko];
    float8v a1 = *(const float8v*)&A[(size_t)a1r*128 + kb*32 + ko];
    short8 ah0, al0, ah1, al1;
#pragma unroll
    for (int j = 0; j < 8; ++j){
      short h, l;
      split2(a0[j], h, l); ah0[j] = h; al0[j] = l;
      split2(a1[j], h, l); ah1[j] = h; al1[j] = l;
    }
#pragma unroll
    for (int nt = 0; nt < 8; ++nt){
      short8 bf = *(const short8*)&Wf[(kb*8 + nt)*512 + lane*8];
      acc[nt][0] = __builtin_amdgcn_mfma_f32_16x16x32_bf16(ah0, bf, acc[nt][0], 0, 0, 0);
      acc[nt][0] = __builtin_amdgcn_mfma_f32_16x16x32_bf16(al0, bf, acc[nt][0], 0, 0, 0);
      acc[nt][1] = __builtin_amdgcn_mfma_f32_16x16x32_bf16(ah1, bf, acc[nt][1], 0, 0, 0);
      acc[nt][1] = __builtin_amdgcn_mfma_f32_16x16x32_bf16(al1, bf, acc[nt][1], 0, 0, 0);
    }
  }

  const int col = lane & 15;
  const int rb  = (lane >> 4) * 4;
#pragma unroll
  for (int nt = 0; nt < 8; ++nt){
    int n = nt*16 + col;
    float bv = bias[n];
#pragma unroll
    for (int mt = 0; mt < 2; ++mt){
#pragma unroll
      for (int r = 0; r < 4; ++r){
        int m = mbase + mt*16 + rb + r;
        if (m < M){
          float v = acc[nt][mt][r] + bv;
          Hout[(size_t)m*128 + n] = f2bf(v > 0.f ? v : 0.f);
        }
      }
    }
  }
}

// ---------------- fused MLP: 2 m-tiles/wave, bf16 weights (1-term), stride-260 LDS ----------------

#define HS 260

__global__ __launch_bounds__(256) void mlp_fused(const uint16_t* __restrict__ Hb,
                                                 const uint16_t* __restrict__ W1f,
                                                 const float* __restrict__ b1,
                                                 const uint16_t* __restrict__ W2f,
                                                 const float* __restrict__ b2,
                                                 float* __restrict__ out, int M){
  __shared__ uint16_t hid[128*HS];
  const int lane = threadIdx.x & 63;
  const int wid = threadIdx.x >> 6;
  const int mbase = blockIdx.x*128 + wid*32;
  const int mr = lane & 15;
  const int a0r = (mbase + mr < M) ? (mbase + mr) : (M-1);
  const int a1r = (mbase + 16 + mr < M) ? (mbase + 16 + mr) : (M-1);
  const int ko = (lane >> 4) << 3;
  const int col = lane & 15;
  const int rb  = (lane >> 4) * 4;

  // phase 1: hidden = relu(Hb @ Wm1 + bm1), K=128, N=256, 1-term bf16
  float4v acc1[16][2];
#pragma unroll
  for (int nt = 0; nt < 16; ++nt){ float4v z = {0.f,0.f,0.f,0.f}; acc1[nt][0] = z; acc1[nt][1] = z; }
#pragma unroll
  for (int kb = 0; kb < 4; ++kb){
    short8 af0 = *(const short8*)&Hb[(size_t)a0r*128 + kb*32 + ko];
    short8 af1 = *(const short8*)&Hb[(size_t)a1r*128 + kb*32 + ko];
#pragma unroll
    for (int nt = 0; nt < 16; ++nt){
      short8 bf = *(const short8*)&W1f[(kb*16 + nt)*512 + lane*8];
      acc1[nt][0] = __builtin_amdgcn_mfma_f32_16x16x32_bf16(af0, bf, acc1[nt][0], 0, 0, 0);
      acc1[nt][1] = __builtin_amdgcn_mfma_f32_16x16x32_bf16(af1, bf, acc1[nt][1], 0, 0, 0);
    }
  }
#pragma unroll
  for (int nt = 0; nt < 16; ++nt){
    float bv = b1[nt*16 + col];
#pragma unroll
    for (int mt = 0; mt < 2; ++mt){
#pragma unroll
      for (int r = 0; r < 4; ++r){
        float v = acc1[nt][mt][r] + bv;
        v = v > 0.f ? v : 0.f;
        hid[(wid*32 + mt*16 + rb + r)*HS + nt*16 + col] = f2bf(v);
      }
    }
  }
  __syncthreads();

  // phase 2: out = hidden @ Wm2 + bm2, K=256, N=40 (padded 48), 1-term bf16
  float4v acc2[3][2];
#pragma unroll
  for (int nt = 0; nt < 3; ++nt){ float4v z = {0.f,0.f,0.f,0.f}; acc2[nt][0] = z; acc2[nt][1] = z; }
#pragma unroll
  for (int kb = 0; kb < 8; ++kb){
    short8 a0 = *(const short8*)&hid[(wid*32 + mr)*HS + kb*32 + ko];
    short8 a1 = *(const short8*)&hid[(wid*32 + 16 + mr)*HS + kb*32 + ko];
#pragma unroll
    for (int nt = 0; nt < 3; ++nt){
      short8 bf = *(const short8*)&W2f[(kb*3 + nt)*512 + lane*8];
      acc2[nt][0] = __builtin_amdgcn_mfma_f32_16x16x32_bf16(a0, bf, acc2[nt][0], 0, 0, 0);
      acc2[nt][1] = __builtin_amdgcn_mfma_f32_16x16x32_bf16(a1, bf, acc2[nt][1], 0, 0, 0);
    }
  }
#pragma unroll
  for (int nt = 0; nt < 3; ++nt){
    int n = nt*16 + col;
    if (n < LL){
      float bv = b2[n];
#pragma unroll
      for (int mt = 0; mt < 2; ++mt){
#pragma unroll
        for (int r = 0; r < 4; ++r){
          int m = mbase + mt*16 + rb + r;
          if (m < M) out[(size_t)m*LL + n] = acc2[nt][mt][r] + bv;
        }
      }
    }
  }
}

// ---------------- launch ----------------

extern "C" void kernel_launch(void* const* d_in, const int* in_sizes, int n_in,
                              void* d_out, int out_size, void* d_ws, size_t ws_size,
                              hipStream_t stream){
  const float* x   = (const float*)d_in[0];
  const int*   ei  = (const int*)d_in[1];
  const float* W0  = (const float*)d_in[2];
  const float* b0  = (const float*)d_in[3];
  const float* W1  = (const float*)d_in[4];
  const float* b1  = (const float*)d_in[5];
  const float* W2  = (const float*)d_in[6];
  const float* b2  = (const float*)d_in[7];
  const float* Wm1 = (const float*)d_in[8];
  const float* bm1 = (const float*)d_in[9];
  const float* Wm2 = (const float*)d_in[10];
  const float* bm2 = (const float*)d_in[11];
  const int* row = ei;
  const int* col = ei + NE;

  char* ws = (char*)d_ws;
  size_t off = 0;
  auto alloc = [&](size_t bytes)->void*{
    void* p = ws + off;
    off += (bytes + 255) & ~(size_t)255;
    return p;
  };
  int*      counts  = (int*)alloc((size_t)NN*4);
  int*      offs    = (int*)alloc(((size_t)NN+1)*4);
  int*      bsums   = (int*)alloc(1024*4);
  float*    dinv    = (float*)alloc((size_t)NN*4);
  int*      rank    = (int*)alloc((size_t)NE*4);
  uint2*    csr_cw  = (uint2*)alloc((size_t)NE*8);
  uint16_t* W0f     = (uint16_t*)alloc(4*8*512*2);
  uint16_t* W1f     = (uint16_t*)alloc(4*8*512*2);
  uint16_t* W2f     = (uint16_t*)alloc(4*8*512*2);
  uint16_t* Wm1f    = (uint16_t*)alloc(4*16*512*2);
  uint16_t* Wm2f    = (uint16_t*)alloc(8*3*512*2);
  uint16_t* hb      = (uint16_t*)alloc((size_t)NN*DD*2);
  float*    A       = (float*)alloc((size_t)NN*DD*4);

  hipMemsetAsync(counts, 0, (size_t)NN*4, stream);
  count_edges<<<(NE+255)/256, 256, 0, stream>>>(row, counts, rank);
  const int NB = (NN+255)/256;
  scan_partial<<<NB, 256, 0, stream>>>(counts, offs, bsums);
  scan_block<<<1, 512, 0, stream>>>(bsums, NB);
  scan_add<<<NB, 256, 0, stream>>>(offs, bsums);
  compute_dinv<<<(NN+255)/256, 256, 0, stream>>>(counts, dinv);
  fill_csr<<<(NE+255)/256, 256, 0, stream>>>(row, col, rank, offs, dinv, csr_cw);

  swz<128,128,8><<<(4*8*512+255)/256, 256, 0, stream>>>(W0, W0f);
  swz<128,128,8><<<(4*8*512+255)/256, 256, 0, stream>>>(W1, W1f);
  swz<128,128,8><<<(4*8*512+255)/256, 256, 0, stream>>>(W2, W2f);
  swz<128,256,16><<<(4*16*512+255)/256, 256, 0, stream>>>(Wm1, Wm1f);
  swz<256,40,3><<<(8*3*512+255)/256, 256, 0, stream>>>(Wm2, Wm2f);

  cvt_bf16<<<(NN*64+255)/256, 256, 0, stream>>>((const float2*)x, (uint32_t*)hb);

  const int AGG_BLOCKS = (NN*64 + 255)/256;
  const int GB128 = (NN + 127)/128;

  agg_b<<<AGG_BLOCKS, 256, 0, stream>>>((const uint32_t*)hb, offs, csr_cw, dinv, (float2*)A);
  gemm_b<<<GB128, 256, 0, stream>>>(A, W0f, b0, hb, NN);

  agg_b<<<AGG_BLOCKS, 256, 0, stream>>>((const uint32_t*)hb, offs, csr_cw, dinv, (float2*)A);
  gemm_b<<<GB128, 256, 0, stream>>>(A, W1f, b1, hb, NN);

  agg_b<<<AGG_BLOCKS, 256, 0, stream>>>((const uint32_t*)hb, offs, csr_cw, dinv, (float2*)A);
  gemm_b<<<GB128, 256, 0, stream>>>(A, W2f, b2, hb, NN);

  mlp_fused<<<GB128, 256, 0, stream>>>(hb, Wm1f, bm1, Wm2f, bm2, (float*)d_out, NN);
}